// Round 9
// baseline (773.088 us; speedup 1.0000x reference)
//
#include <hip/hip_runtime.h>
#include <cstddef>
#include <cstdint>

#define NN 16384
#define FF 64
#define BM 64
#define BK 32               // halved: 32 KB LDS/block -> 4 blocks/CU resident
#define SK 4
#define KQ (NN / SK)        // 4096 k per split-K slice
#define NC (KQ / BK)        // 128 chunks per block

typedef __attribute__((ext_vector_type(8))) short bf16x8;
typedef __attribute__((ext_vector_type(4))) float f32x4;
typedef unsigned short ushort_t;

#define GLOBAL_AS __attribute__((address_space(1)))
#define LDS_AS    __attribute__((address_space(3)))

// truncate-split: f = hi + lo (+ ~2^-16 rel dropped); hi/lo as bf16 bit patterns
__device__ __forceinline__ void f32_split(float f, ushort_t& h, ushort_t& l) {
    unsigned u = __builtin_bit_cast(unsigned, f);
    h = (ushort_t)(u >> 16);
    float hf = __builtin_bit_cast(float, u & 0xFFFF0000u);
    float lo = f - hf;                       // exact (Sterbenz)
    l = (ushort_t)(__builtin_bit_cast(unsigned, lo) >> 16);
}

// ---------------------------------------------------------------------------
// Hop 0: Th/Tl = splitT(x) ; out = bias + x @ W0.   grid 256, 64 rows/block.
// ---------------------------------------------------------------------------
__global__ __launch_bounds__(256) void convT_init(
    const float* __restrict__ X, ushort_t* __restrict__ Th,
    ushort_t* __restrict__ Tl, const float* __restrict__ W0,
    const float* __restrict__ bias, float* __restrict__ out)
{
    __shared__ float S[64][68];
    __shared__ float W[64][64];
    const int t = threadIdx.x;
    const int rb = blockIdx.x * 64;
    {
        const int row = t >> 2;
        const int c0 = (t & 3) * 16;
        const float* src = X + (size_t)(rb + row) * FF + c0;
        *(float4*)&S[row][c0 + 0]  = *(const float4*)(src + 0);
        *(float4*)&S[row][c0 + 4]  = *(const float4*)(src + 4);
        *(float4*)&S[row][c0 + 8]  = *(const float4*)(src + 8);
        *(float4*)&S[row][c0 + 12] = *(const float4*)(src + 12);
        float4* wd = (float4*)&W[0][0];
        const float4* ws = (const float4*)W0;
#pragma unroll
        for (int j = 0; j < 4; ++j) wd[t * 4 + j] = ws[t * 4 + j];
    }
    __syncthreads();
    // split-transpose
    {
        const int cc = t >> 2;
        const int r0 = (t & 3) * 16;
        ushort_t hh[16], ll[16];
#pragma unroll
        for (int i = 0; i < 16; ++i) f32_split(S[r0 + i][cc], hh[i], ll[i]);
        unsigned wh[8], wl[8];
#pragma unroll
        for (int j = 0; j < 8; ++j) {
            wh[j] = (unsigned)hh[2 * j] | ((unsigned)hh[2 * j + 1] << 16);
            wl[j] = (unsigned)ll[2 * j] | ((unsigned)ll[2 * j + 1] << 16);
        }
        const size_t o = (size_t)cc * NN + rb + r0;
        *(uint4*)(Th + o)     = make_uint4(wh[0], wh[1], wh[2], wh[3]);
        *(uint4*)(Th + o + 8) = make_uint4(wh[4], wh[5], wh[6], wh[7]);
        *(uint4*)(Tl + o)     = make_uint4(wl[0], wl[1], wl[2], wl[3]);
        *(uint4*)(Tl + o + 8) = make_uint4(wl[4], wl[5], wl[6], wl[7]);
    }
    // out = bias + x@W0 : 2 rows x 8 cols per thread
    {
        const int row0 = (t >> 3) * 2;
        const int col0 = (t & 7) * 8;
        float acc[2][8];
        const float4 b0 = *(const float4*)(bias + col0);
        const float4 b1 = *(const float4*)(bias + col0 + 4);
#pragma unroll
        for (int r = 0; r < 2; ++r) {
            acc[r][0] = b0.x; acc[r][1] = b0.y; acc[r][2] = b0.z; acc[r][3] = b0.w;
            acc[r][4] = b1.x; acc[r][5] = b1.y; acc[r][6] = b1.z; acc[r][7] = b1.w;
        }
#pragma unroll
        for (int f = 0; f < FF; ++f) {
            const float x0 = S[row0][f];
            const float x1 = S[row0 + 1][f];
            const float4 w0 = *(const float4*)&W[f][col0];
            const float4 w1 = *(const float4*)&W[f][col0 + 4];
            acc[0][0] += x0 * w0.x; acc[0][1] += x0 * w0.y;
            acc[0][2] += x0 * w0.z; acc[0][3] += x0 * w0.w;
            acc[0][4] += x0 * w1.x; acc[0][5] += x0 * w1.y;
            acc[0][6] += x0 * w1.z; acc[0][7] += x0 * w1.w;
            acc[1][0] += x1 * w0.x; acc[1][1] += x1 * w0.y;
            acc[1][2] += x1 * w0.z; acc[1][3] += x1 * w0.w;
            acc[1][4] += x1 * w1.x; acc[1][5] += x1 * w1.y;
            acc[1][6] += x1 * w1.z; acc[1][7] += x1 * w1.w;
        }
#pragma unroll
        for (int r = 0; r < 2; ++r) {
            const size_t o = (size_t)(rb + row0 + r) * FF + col0;
            float4 v0, v1;
            v0.x = acc[r][0]; v0.y = acc[r][1]; v0.z = acc[r][2]; v0.w = acc[r][3];
            v1.x = acc[r][4]; v1.y = acc[r][5]; v1.z = acc[r][6]; v1.w = acc[r][7];
            *(float4*)(out + o) = v0;
            *(float4*)(out + o + 4) = v1;
        }
    }
}

// ---------------------------------------------------------------------------
// P[s] = L[:, kslice_s] @ T[kslice_s, :]   via bf16 hi/lo-split MFMA.
// grid SK*256: s = bx>>8, m = bx&255. 256 thr = 4 waves (2x2 of 32x32 tiles).
// BK=32: 32 KB LDS -> 4 blocks/CU resident (16 waves/CU) to cover the
// per-barrier vmcnt drain with cross-block TLP.
// A layout: [64 rows][4 slots of 16B], slot = (k/8) ^ (row&3)  (2-way free)
// B layout: [64 cols][4 slots of 16B], slot = (k/8) ^ (col&3), written by
//           global_load_lds with linear dest + pre-swizzled global source.
// ---------------------------------------------------------------------------
__global__ __launch_bounds__(256) void cheb_gemm_mfma(
    const float* __restrict__ L, const ushort_t* __restrict__ Th,
    const ushort_t* __restrict__ Tl, float* __restrict__ P)
{
    __shared__ ushort_t Ah[2][BM * BK];   // 8 KB
    __shared__ ushort_t Al[2][BM * BK];   // 8 KB
    __shared__ ushort_t Bh[2][FF * BK];   // 8 KB
    __shared__ ushort_t Bl[2][FF * BK];   // 8 KB

    const int tid  = threadIdx.x;
    const int lane = tid & 63;
    const int w    = tid >> 6;
    const int s    = blockIdx.x >> 8;
    const int m    = blockIdx.x & 255;
    const int row0g = m * BM;
    const int kbase = s * KQ;

    const int wm = w >> 1, wn = w & 1;      // wave tile (32x32) coords
    const int frow = lane & 15;             // row (A) / col (B) within 16-tile
    const int fkq  = lane >> 4;             // k-group 0..3 (8 bf16 each)

    // A staging: thread owns row ar (0..63), k-group akq (0..3)
    const int ar  = tid >> 2;
    const int akq = tid & 3;
    const int abyte = ar * 64 + ((akq ^ (ar & 3)) << 4);

    // B staging: wave picks hi/lo tile and 4 col-octets
    const ushort_t* Tsrc = (w & 1) ? Tl : Th;
    const int boct0 = (w >> 1) * 4;

    f32x4 acc[2][2];
#pragma unroll
    for (int i = 0; i < 2; ++i)
#pragma unroll
        for (int j = 0; j < 2; ++j) acc[i][j] = (f32x4)0.f;

    float4 va0, va1;

    const float* Labase = L + (size_t)(row0g + ar) * NN + kbase + akq * 8;

#define ISSUE_B(c, slot)                                                        \
    {                                                                           \
        const size_t kc = (size_t)(c) * BK;                                     \
        char* bbase = (char*)((w & 1) ? Bl[slot] : Bh[slot]);                   \
        _Pragma("unroll")                                                       \
        for (int j = 0; j < 2; ++j) {                                           \
            const int oct2 = boct0 + 2 * j;       /* wave-uniform */            \
            const int col = oct2 * 8 + (lane >> 5) * 8 + ((lane & 31) >> 2);    \
            const int sg = (lane & 3) ^ (col & 3);                              \
            const ushort_t* g = Tsrc + (size_t)col * NN + kbase + kc + sg * 8;  \
            __builtin_amdgcn_global_load_lds((const GLOBAL_AS void*)g,          \
                (LDS_AS void*)(bbase + oct2 * 512), 16, 0, 0);                  \
        }                                                                       \
    }

#define LOAD_A(c)                                                               \
    {                                                                           \
        const float* g = Labase + (size_t)(c) * BK;                             \
        va0 = *(const float4*)(g);                                              \
        va1 = *(const float4*)(g + 4);                                          \
    }

#define CONV_WRITE_A(slot)                                                      \
    {                                                                           \
        ushort_t h0, h1, h2, h3, l0, l1, l2, l3;                                \
        ushort_t h4, h5, h6, h7, l4, l5, l6, l7;                                \
        f32_split(va0.x, h0, l0); f32_split(va0.y, h1, l1);                     \
        f32_split(va0.z, h2, l2); f32_split(va0.w, h3, l3);                     \
        f32_split(va1.x, h4, l4); f32_split(va1.y, h5, l5);                     \
        f32_split(va1.z, h6, l6); f32_split(va1.w, h7, l7);                     \
        const uint4 hv = make_uint4(                                            \
            (unsigned)h0 | ((unsigned)h1 << 16),                                \
            (unsigned)h2 | ((unsigned)h3 << 16),                                \
            (unsigned)h4 | ((unsigned)h5 << 16),                                \
            (unsigned)h6 | ((unsigned)h7 << 16));                               \
        const uint4 lv = make_uint4(                                            \
            (unsigned)l0 | ((unsigned)l1 << 16),                                \
            (unsigned)l2 | ((unsigned)l3 << 16),                                \
            (unsigned)l4 | ((unsigned)l5 << 16),                                \
            (unsigned)l6 | ((unsigned)l7 << 16));                               \
        *(uint4*)((char*)Ah[slot] + abyte) = hv;                                \
        *(uint4*)((char*)Al[slot] + abyte) = lv;                                \
    }

#define COMPUTE(slot)                                                           \
    {                                                                           \
        const char* ahb = (const char*)Ah[slot];                                \
        const char* alb = (const char*)Al[slot];                                \
        const char* bhb = (const char*)Bh[slot];                                \
        const char* blb = (const char*)Bl[slot];                                \
        bf16x8 Afh[2], Afl[2], Bfh[2], Bfl[2];                                  \
        _Pragma("unroll")                                                       \
        for (int mt = 0; mt < 2; ++mt) {                                        \
            const int row = wm * 32 + mt * 16 + frow;                           \
            const int off = row * 64 + ((fkq ^ (row & 3)) << 4);                \
            Afh[mt] = *(const bf16x8*)(ahb + off);                              \
            Afl[mt] = *(const bf16x8*)(alb + off);                              \
        }                                                                       \
        _Pragma("unroll")                                                       \
        for (int nt = 0; nt < 2; ++nt) {                                        \
            const int col = wn * 32 + nt * 16 + frow;                           \
            const int off = col * 64 + ((fkq ^ (col & 3)) << 4);                \
            Bfh[nt] = *(const bf16x8*)(bhb + off);                              \
            Bfl[nt] = *(const bf16x8*)(blb + off);                              \
        }                                                                       \
        _Pragma("unroll")                                                       \
        for (int mt = 0; mt < 2; ++mt)                                          \
            _Pragma("unroll")                                                   \
            for (int nt = 0; nt < 2; ++nt) {                                    \
                acc[mt][nt] = __builtin_amdgcn_mfma_f32_16x16x32_bf16(          \
                    Afh[mt], Bfh[nt], acc[mt][nt], 0, 0, 0);                    \
                acc[mt][nt] = __builtin_amdgcn_mfma_f32_16x16x32_bf16(          \
                    Afh[mt], Bfl[nt], acc[mt][nt], 0, 0, 0);                    \
                acc[mt][nt] = __builtin_amdgcn_mfma_f32_16x16x32_bf16(          \
                    Afl[mt], Bfh[nt], acc[mt][nt], 0, 0, 0);                    \
            }                                                                   \
    }

    // ---- prologue: chunk 0 -> slot 0
    ISSUE_B(0, 0)
    LOAD_A(0)
    CONV_WRITE_A(0)
    __syncthreads();

#pragma unroll 1
    for (int c = 0; c < NC; ++c) {
        const int slot = c & 1;
        if (c + 1 < NC) {
            ISSUE_B(c + 1, slot ^ 1)
            LOAD_A(c + 1)
        }
        COMPUTE(slot)
        if (c + 1 < NC) CONV_WRITE_A(slot ^ 1)
        __syncthreads();
    }

    // ---- write partial: C/D layout col=lane&15, row=(lane>>4)*4+r  (m89)
    float* Pp = P + (size_t)s * NN * FF;
#pragma unroll
    for (int mt = 0; mt < 2; ++mt)
#pragma unroll
        for (int nt = 0; nt < 2; ++nt) {
            const int row = row0g + wm * 32 + mt * 16 + (lane >> 4) * 4;
            const int col = wn * 32 + nt * 16 + frow;
#pragma unroll
            for (int r = 0; r < 4; ++r)
                Pp[(size_t)(row + r) * FF + col] = acc[mt][nt][r];
        }
#undef ISSUE_B
#undef LOAD_A
#undef CONV_WRITE_A
#undef COMPUTE
}

// ---------------------------------------------------------------------------
// Fused per-hop epilogue, 32 rows/block (grid 512):
//   t = alpha*(P0+P1+P2+P3) + beta*Tsub ; [Tstore]=t ; [Thn/Tln]=splitT(t) ;
//   out += t @ Wk
// ---------------------------------------------------------------------------
__global__ __launch_bounds__(256) void post_hop(
    const float* __restrict__ P,
    const float* __restrict__ Tsub, const float* __restrict__ Wk,
    float* __restrict__ Tstore, ushort_t* __restrict__ Thn,
    ushort_t* __restrict__ Tln, float* __restrict__ out,
    float alpha, float beta)
{
    __shared__ float ST[64][33];   // ST[f][row]
    __shared__ float WK[64][64];
    const int t = threadIdx.x;
    const int rb = blockIdx.x * 32;
    const size_t M1 = (size_t)NN * FF;

    {
        float4* wd = (float4*)&WK[0][0];
        const float4* ws = (const float4*)Wk;
#pragma unroll
        for (int j = 0; j < 4; ++j) wd[t * 4 + j] = ws[t * 4 + j];
    }

    const int row = t >> 3;             // 0..31
    const int c0 = (t & 7) * 8;
    const size_t o = (size_t)(rb + row) * FF + c0;

    // phase A: t = alpha*sum(P) + beta*Tsub -> ST (transposed) [+ Tstore]
    {
        float tv[8];
#pragma unroll
        for (int half = 0; half < 2; ++half) {
            const size_t oo = o + 4 * half;
            float4 a0 = *(const float4*)(P + oo);
            const float4 a1 = *(const float4*)(P + M1 + oo);
            const float4 a2 = *(const float4*)(P + 2 * M1 + oo);
            const float4 a3 = *(const float4*)(P + 3 * M1 + oo);
            a0.x += a1.x + a2.x + a3.x; a0.y += a1.y + a2.y + a3.y;
            a0.z += a1.z + a2.z + a3.z; a0.w += a1.w + a2.w + a3.w;
            tv[4 * half + 0] = alpha * a0.x; tv[4 * half + 1] = alpha * a0.y;
            tv[4 * half + 2] = alpha * a0.z; tv[4 * half + 3] = alpha * a0.w;
        }
        if (beta != 0.f) {
            const float4 s0 = *(const float4*)(Tsub + o);
            const float4 s1 = *(const float4*)(Tsub + o + 4);
            tv[0] += beta * s0.x; tv[1] += beta * s0.y;
            tv[2] += beta * s0.z; tv[3] += beta * s0.w;
            tv[4] += beta * s1.x; tv[5] += beta * s1.y;
            tv[6] += beta * s1.z; tv[7] += beta * s1.w;
        }
        if (Tstore) {
            float4 v0, v1;
            v0.x = tv[0]; v0.y = tv[1]; v0.z = tv[2]; v0.w = tv[3];
            v1.x = tv[4]; v1.y = tv[5]; v1.z = tv[6]; v1.w = tv[7];
            *(float4*)(Tstore + o) = v0;
            *(float4*)(Tstore + o + 4) = v1;
        }
#pragma unroll
        for (int j = 0; j < 8; ++j) ST[c0 + j][row] = tv[j];
    }
    __syncthreads();

    // phase B: split-transpose -> Thn/Tln ([64][N] layout for global_load_lds)
    if (Thn) {
        const int f = t >> 2;           // 0..63
        const int r0 = (t & 3) * 8;     // 0,8,16,24
        ushort_t hh[8], ll[8];
#pragma unroll
        for (int i = 0; i < 8; ++i) f32_split(ST[f][r0 + i], hh[i], ll[i]);
        unsigned wh[4], wl[4];
#pragma unroll
        for (int j = 0; j < 4; ++j) {
            wh[j] = (unsigned)hh[2 * j] | ((unsigned)hh[2 * j + 1] << 16);
            wl[j] = (unsigned)ll[2 * j] | ((unsigned)ll[2 * j + 1] << 16);
        }
        const size_t ob = (size_t)f * NN + rb + r0;
        *(uint4*)(Thn + ob) = make_uint4(wh[0], wh[1], wh[2], wh[3]);
        *(uint4*)(Tln + ob) = make_uint4(wl[0], wl[1], wl[2], wl[3]);
    }

    // phase C: out += t @ Wk
    {
        float4 a0 = *(const float4*)(out + o);
        float4 a1 = *(const float4*)(out + o + 4);
#pragma unroll
        for (int f = 0; f < FF; ++f) {
            const float sv = ST[f][row];
            const float4 w0 = *(const float4*)&WK[f][c0];
            const float4 w1 = *(const float4*)&WK[f][c0 + 4];
            a0.x += sv * w0.x; a0.y += sv * w0.y;
            a0.z += sv * w0.z; a0.w += sv * w0.w;
            a1.x += sv * w1.x; a1.y += sv * w1.y;
            a1.z += sv * w1.z; a1.w += sv * w1.w;
        }
        *(float4*)(out + o) = a0;
        *(float4*)(out + o + 4) = a1;
    }
}

extern "C" void kernel_launch(void* const* d_in, const int* in_sizes, int n_in,
                              void* d_out, int out_size, void* d_ws, size_t ws_size,
                              hipStream_t stream)
{
    const float* x    = (const float*)d_in[0];
    const float* L    = (const float*)d_in[1];
    const float* W    = (const float*)d_in[2];   // (4, 64, 64)
    const float* bias = (const float*)d_in[3];
    float* out = (float*)d_out;

    const size_t M1 = (size_t)NN * FF;           // 1,048,576 elems
    float* wsf = (float*)d_ws;
    float* T1 = wsf;                             // 4 MB
    float* P  = wsf + M1;                        // 4 partials, 16 MB
    ushort_t* ThA = (ushort_t*)(wsf + 5 * M1);   // 2 MB each
    ushort_t* TlA = ThA + M1;
    ushort_t* ThB = TlA + M1;
    ushort_t* TlB = ThB + M1;

    const dim3 gc(NN / 64), bc(256);             // convT_init: 256 blocks
    const dim3 gg(SK * 256), bg(256);            // gemm: 1024 blocks
    const dim3 gp(NN / 32), bp(256);             // post_hop: 512 blocks

    // hop 0: ThA/TlA = splitT(x) ; out = bias + x@W0
    convT_init<<<gc, bc, 0, stream>>>(x, ThA, TlA, W + 0 * FF * FF, bias, out);
    // hop 1: T1 = L@x ; ThB/TlB = splitT(T1) ; out += T1@W1
    cheb_gemm_mfma<<<gg, bg, 0, stream>>>(L, ThA, TlA, P);
    post_hop<<<gp, bp, 0, stream>>>(P, x, W + 1 * FF * FF,
                                    T1, ThB, TlB, out, 1.f, 0.f);
    // hop 2: T2 = 2*(L@T1) - x ; ThA/TlA = splitT(T2) ; out += T2@W2
    cheb_gemm_mfma<<<gg, bg, 0, stream>>>(L, ThB, TlB, P);
    post_hop<<<gp, bp, 0, stream>>>(P, x, W + 2 * FF * FF,
                                    nullptr, ThA, TlA, out, 2.f, -1.f);
    // hop 3: T3 = 2*(L@T2) - T1 ; out += T3@W3
    cheb_gemm_mfma<<<gg, bg, 0, stream>>>(L, ThA, TlA, P);
    post_hop<<<gp, bp, 0, stream>>>(P, T1, W + 3 * FF * FF,
                                    nullptr, nullptr, nullptr, out, 2.f, -1.f);
}

// Round 10
// 763.789 us; speedup vs baseline: 1.0122x; 1.0122x over previous
//
#include <hip/hip_runtime.h>
#include <cstddef>
#include <cstdint>

#define NN 16384
#define FF 64
#define BM 64
#define BK 64
#define SK 4
#define KQ (NN / SK)        // 4096 k per split-K slice
#define NC (KQ / BK)        // 64 chunks per block (even)

typedef __attribute__((ext_vector_type(8))) short bf16x8;
typedef __attribute__((ext_vector_type(4))) float f32x4;
typedef unsigned short ushort_t;

#define GLOBAL_AS __attribute__((address_space(1)))
#define LDS_AS    __attribute__((address_space(3)))

#define VMCNT8   asm volatile("s_waitcnt vmcnt(8)" ::: "memory")
#define VMCNT0   asm volatile("s_waitcnt vmcnt(0)" ::: "memory")
#define LGKMCNT0 asm volatile("s_waitcnt lgkmcnt(0)" ::: "memory")
#define SCHEDB   __builtin_amdgcn_sched_barrier(0)
#define BARRIER  __builtin_amdgcn_s_barrier()

// truncate-split: f = hi + lo (+ ~2^-16 rel dropped); hi/lo as bf16 bit patterns
__device__ __forceinline__ void f32_split(float f, ushort_t& h, ushort_t& l) {
    unsigned u = __builtin_bit_cast(unsigned, f);
    h = (ushort_t)(u >> 16);
    float hf = __builtin_bit_cast(float, u & 0xFFFF0000u);
    float lo = f - hf;                       // exact (Sterbenz)
    l = (ushort_t)(__builtin_bit_cast(unsigned, lo) >> 16);
}

// ---------------------------------------------------------------------------
// Hop 0: Th/Tl = splitT(x) ; out = bias + x @ W0.   grid 256, 64 rows/block.
// ---------------------------------------------------------------------------
__global__ __launch_bounds__(256) void convT_init(
    const float* __restrict__ X, ushort_t* __restrict__ Th,
    ushort_t* __restrict__ Tl, const float* __restrict__ W0,
    const float* __restrict__ bias, float* __restrict__ out)
{
    __shared__ float S[64][68];
    __shared__ float W[64][64];
    const int t = threadIdx.x;
    const int rb = blockIdx.x * 64;
    {
        const int row = t >> 2;
        const int c0 = (t & 3) * 16;
        const float* src = X + (size_t)(rb + row) * FF + c0;
        *(float4*)&S[row][c0 + 0]  = *(const float4*)(src + 0);
        *(float4*)&S[row][c0 + 4]  = *(const float4*)(src + 4);
        *(float4*)&S[row][c0 + 8]  = *(const float4*)(src + 8);
        *(float4*)&S[row][c0 + 12] = *(const float4*)(src + 12);
        float4* wd = (float4*)&W[0][0];
        const float4* ws = (const float4*)W0;
#pragma unroll
        for (int j = 0; j < 4; ++j) wd[t * 4 + j] = ws[t * 4 + j];
    }
    __syncthreads();
    // split-transpose
    {
        const int cc = t >> 2;
        const int r0 = (t & 3) * 16;
        ushort_t hh[16], ll[16];
#pragma unroll
        for (int i = 0; i < 16; ++i) f32_split(S[r0 + i][cc], hh[i], ll[i]);
        unsigned wh[8], wl[8];
#pragma unroll
        for (int j = 0; j < 8; ++j) {
            wh[j] = (unsigned)hh[2 * j] | ((unsigned)hh[2 * j + 1] << 16);
            wl[j] = (unsigned)ll[2 * j] | ((unsigned)ll[2 * j + 1] << 16);
        }
        const size_t o = (size_t)cc * NN + rb + r0;
        *(uint4*)(Th + o)     = make_uint4(wh[0], wh[1], wh[2], wh[3]);
        *(uint4*)(Th + o + 8) = make_uint4(wh[4], wh[5], wh[6], wh[7]);
        *(uint4*)(Tl + o)     = make_uint4(wl[0], wl[1], wl[2], wl[3]);
        *(uint4*)(Tl + o + 8) = make_uint4(wl[4], wl[5], wl[6], wl[7]);
    }
    // out = bias + x@W0 : 2 rows x 8 cols per thread
    {
        const int row0 = (t >> 3) * 2;
        const int col0 = (t & 7) * 8;
        float acc[2][8];
        const float4 b0 = *(const float4*)(bias + col0);
        const float4 b1 = *(const float4*)(bias + col0 + 4);
#pragma unroll
        for (int r = 0; r < 2; ++r) {
            acc[r][0] = b0.x; acc[r][1] = b0.y; acc[r][2] = b0.z; acc[r][3] = b0.w;
            acc[r][4] = b1.x; acc[r][5] = b1.y; acc[r][6] = b1.z; acc[r][7] = b1.w;
        }
#pragma unroll
        for (int f = 0; f < FF; ++f) {
            const float x0 = S[row0][f];
            const float x1 = S[row0 + 1][f];
            const float4 w0 = *(const float4*)&W[f][col0];
            const float4 w1 = *(const float4*)&W[f][col0 + 4];
            acc[0][0] += x0 * w0.x; acc[0][1] += x0 * w0.y;
            acc[0][2] += x0 * w0.z; acc[0][3] += x0 * w0.w;
            acc[0][4] += x0 * w1.x; acc[0][5] += x0 * w1.y;
            acc[0][6] += x0 * w1.z; acc[0][7] += x0 * w1.w;
            acc[1][0] += x1 * w0.x; acc[1][1] += x1 * w0.y;
            acc[1][2] += x1 * w0.z; acc[1][3] += x1 * w0.w;
            acc[1][4] += x1 * w1.x; acc[1][5] += x1 * w1.y;
            acc[1][6] += x1 * w1.z; acc[1][7] += x1 * w1.w;
        }
#pragma unroll
        for (int r = 0; r < 2; ++r) {
            const size_t o = (size_t)(rb + row0 + r) * FF + col0;
            float4 v0, v1;
            v0.x = acc[r][0]; v0.y = acc[r][1]; v0.z = acc[r][2]; v0.w = acc[r][3];
            v1.x = acc[r][4]; v1.y = acc[r][5]; v1.z = acc[r][6]; v1.w = acc[r][7];
            *(float4*)(out + o) = v0;
            *(float4*)(out + o + 4) = v1;
        }
    }
}

// ---------------------------------------------------------------------------
// P[s] = L[:, kslice_s] @ T[kslice_s, :]   via bf16 hi/lo-split MFMA.
// grid SK*256: s = bx>>8, m = bx&255. 256 thr = 4 waves (2x2 of 32x32 tiles).
// Counted-vmcnt pipeline (T3/T4-lite): raw s_barrier + vmcnt(8); loads for
// chunk c+2 stay in flight ACROSS the barrier. A ring-2 LDS, B ring-3 LDS
// (80 KB -> 2 blocks/CU, same as R8). Issue order per iter: A(c+2) x4 then
// B(c+2) x4 => vmcnt(8) before CONV_WRITE_A(c+1) guarantees A(c+1) regs AND
// B(c+1) landed in LDS.
// ---------------------------------------------------------------------------
__global__ __launch_bounds__(256) void cheb_gemm_mfma(
    const float* __restrict__ L, const ushort_t* __restrict__ Th,
    const ushort_t* __restrict__ Tl, float* __restrict__ P)
{
    __shared__ ushort_t Ah[2][BM * BK];   // 16 KB
    __shared__ ushort_t Al[2][BM * BK];   // 16 KB
    __shared__ ushort_t Bh[3][FF * BK];   // 24 KB
    __shared__ ushort_t Bl[3][FF * BK];   // 24 KB

    const int tid  = threadIdx.x;
    const int lane = tid & 63;
    const int w    = tid >> 6;
    const int s    = blockIdx.x >> 8;
    const int m    = blockIdx.x & 255;
    const int row0g = m * BM;
    const int kbase = s * KQ;

    const int wm = w >> 1, wn = w & 1;      // wave tile (32x32) coords
    const int frow = lane & 15;             // row (A) / col (B) within 16-tile
    const int fk8  = (lane >> 4) * 8;       // k-offset base

    // A staging: thread covers rows arow+16p, k = akq*4..+3
    const int arow = w * 4 + (lane >> 4);
    const int akq  = lane & 15;
    const int axor = (arow & 7) << 4;

    // B staging: wave picks hi/lo tile and 4 col-octets
    const ushort_t* Tsrc = (w & 1) ? Tl : Th;
    const int boct0 = (w >> 1) * 4;

    f32x4 acc[2][2];
#pragma unroll
    for (int i = 0; i < 2; ++i)
#pragma unroll
        for (int j = 0; j < 2; ++j) acc[i][j] = (f32x4)0.f;

    float4 vaA[4], vaB[4];   // statically named A-reg double buffer (rule 20)

    const float* Labase = L + (size_t)(row0g + arow) * NN + kbase + akq * 4;

#define ISSUE_B(c, sb)                                                          \
    {                                                                           \
        const size_t kc = (size_t)(c) * BK;                                     \
        char* bbase = (char*)((w & 1) ? Bl[sb] : Bh[sb]);                       \
        _Pragma("unroll")                                                       \
        for (int o = 0; o < 4; ++o) {                                           \
            const int oct = boct0 + o;                                          \
            const int col = oct * 8 + (lane >> 3);                              \
            const ushort_t* g = Tsrc + (size_t)col * NN + kbase + kc            \
                                + (((lane & 7) ^ (col & 7)) * 8);               \
            __builtin_amdgcn_global_load_lds((const GLOBAL_AS void*)g,          \
                (LDS_AS void*)(bbase + oct * 1024), 16, 0, 0);                  \
        }                                                                       \
    }

#define LOAD_A(va, c)                                                           \
    {                                                                           \
        const float* g = Labase + (size_t)(c) * BK;                             \
        va[0] = *(const float4*)(g);                                            \
        va[1] = *(const float4*)(g + (size_t)16 * NN);                          \
        va[2] = *(const float4*)(g + (size_t)32 * NN);                          \
        va[3] = *(const float4*)(g + (size_t)48 * NN);                          \
    }

#define CONV_WRITE_A(va, sa)                                                    \
    {                                                                           \
        char* ahb = (char*)Ah[sa];                                              \
        char* alb = (char*)Al[sa];                                              \
        _Pragma("unroll")                                                       \
        for (int p = 0; p < 4; ++p) {                                           \
            const int r = arow + p * 16;                                        \
            ushort_t h0, h1, h2, h3, l0, l1, l2, l3;                            \
            f32_split(va[p].x, h0, l0);                                         \
            f32_split(va[p].y, h1, l1);                                         \
            f32_split(va[p].z, h2, l2);                                         \
            f32_split(va[p].w, h3, l3);                                         \
            const unsigned hi01 = (unsigned)h0 | ((unsigned)h1 << 16);          \
            const unsigned hi23 = (unsigned)h2 | ((unsigned)h3 << 16);          \
            const unsigned lo01 = (unsigned)l0 | ((unsigned)l1 << 16);          \
            const unsigned lo23 = (unsigned)l2 | ((unsigned)l3 << 16);          \
            const int byte = (r * 128 + akq * 8) ^ axor;                        \
            *(uint2*)(ahb + byte) = make_uint2(hi01, hi23);                     \
            *(uint2*)(alb + byte) = make_uint2(lo01, lo23);                     \
        }                                                                       \
    }

#define COMPUTE(sa, sb)                                                         \
    {                                                                           \
        const char* ahb = (const char*)Ah[sa];                                  \
        const char* alb = (const char*)Al[sa];                                  \
        const char* bhb = (const char*)Bh[sb];                                  \
        const char* blb = (const char*)Bl[sb];                                  \
        _Pragma("unroll")                                                       \
        for (int ks = 0; ks < 2; ++ks) {                                        \
            const int kk = ks * 32 + fk8;                                       \
            bf16x8 Afh[2], Afl[2], Bfh[2], Bfl[2];                              \
            _Pragma("unroll")                                                   \
            for (int mt = 0; mt < 2; ++mt) {                                    \
                const int row = wm * 32 + mt * 16 + frow;                       \
                const int off = (row * 128 + kk * 2) ^ ((row & 7) << 4);        \
                Afh[mt] = *(const bf16x8*)(ahb + off);                          \
                Afl[mt] = *(const bf16x8*)(alb + off);                          \
            }                                                                   \
            _Pragma("unroll")                                                   \
            for (int nt = 0; nt < 2; ++nt) {                                    \
                const int col = wn * 32 + nt * 16 + frow;                       \
                const int off = (col * 128 + kk * 2) ^ ((col & 7) << 4);        \
                Bfh[nt] = *(const bf16x8*)(bhb + off);                          \
                Bfl[nt] = *(const bf16x8*)(blb + off);                          \
            }                                                                   \
            _Pragma("unroll")                                                   \
            for (int mt = 0; mt < 2; ++mt)                                      \
                _Pragma("unroll")                                               \
                for (int nt = 0; nt < 2; ++nt) {                                \
                    acc[mt][nt] = __builtin_amdgcn_mfma_f32_16x16x32_bf16(      \
                        Afh[mt], Bfh[nt], acc[mt][nt], 0, 0, 0);                \
                    acc[mt][nt] = __builtin_amdgcn_mfma_f32_16x16x32_bf16(      \
                        Afh[mt], Bfl[nt], acc[mt][nt], 0, 0, 0);                \
                    acc[mt][nt] = __builtin_amdgcn_mfma_f32_16x16x32_bf16(      \
                        Afl[mt], Bfh[nt], acc[mt][nt], 0, 0, 0);                \
                }                                                               \
        }                                                                       \
    }

    // ---- prologue: issue chunks 0,1; stage chunk 0
    LOAD_A(vaA, 0)
    ISSUE_B(0, 0)
    LOAD_A(vaB, 1)
    ISSUE_B(1, 1)
    SCHEDB;
    VMCNT8;                  // A(0) regs ready, B(0) landed (A1,B1 in flight)
    SCHEDB;
    CONV_WRITE_A(vaA, 0)
    LGKMCNT0;
    BARRIER;
    SCHEDB;

#pragma unroll 1
    for (int c = 0; c < NC; c += 2) {
        // ---- even chunk c: compute (A slot 0, B slot c%3); write A(c+1)
        if (c + 2 < NC) {
            LOAD_A(vaA, c + 2)
            ISSUE_B(c + 2, (c + 2) % 3)
            SCHEDB;
        }
        COMPUTE(0, c % 3)
        if (c + 2 < NC) { VMCNT8; } else { VMCNT0; }
        SCHEDB;
        CONV_WRITE_A(vaB, 1)        // A(c+1) -> slot 1
        LGKMCNT0;
        BARRIER;
        SCHEDB;

        // ---- odd chunk c+1: compute (A slot 1, B slot (c+1)%3); write A(c+2)
        if (c + 3 < NC) {
            LOAD_A(vaB, c + 3)
            ISSUE_B(c + 3, (c + 3) % 3)
            SCHEDB;
        }
        COMPUTE(1, (c + 1) % 3)
        if (c + 2 < NC) {
            if (c + 3 < NC) { VMCNT8; } else { VMCNT0; }
            SCHEDB;
            CONV_WRITE_A(vaA, 0)    // A(c+2) -> slot 0
            LGKMCNT0;
            BARRIER;
            SCHEDB;
        }
    }

    // ---- write partial: C/D layout col=lane&15, row=(lane>>4)*4+r  (m89)
    float* Pp = P + (size_t)s * NN * FF;
#pragma unroll
    for (int mt = 0; mt < 2; ++mt)
#pragma unroll
        for (int nt = 0; nt < 2; ++nt) {
            const int row = row0g + wm * 32 + mt * 16 + (lane >> 4) * 4;
            const int col = wn * 32 + nt * 16 + frow;
#pragma unroll
            for (int r = 0; r < 4; ++r)
                Pp[(size_t)(row + r) * FF + col] = acc[mt][nt][r];
        }
#undef ISSUE_B
#undef LOAD_A
#undef CONV_WRITE_A
#undef COMPUTE
}

// ---------------------------------------------------------------------------
// Fused per-hop epilogue, 32 rows/block (grid 512):
//   t = alpha*(P0+P1+P2+P3) + beta*Tsub ; [Tstore]=t ; [Thn/Tln]=splitT(t) ;
//   out += t @ Wk
// ---------------------------------------------------------------------------
__global__ __launch_bounds__(256) void post_hop(
    const float* __restrict__ P,
    const float* __restrict__ Tsub, const float* __restrict__ Wk,
    float* __restrict__ Tstore, ushort_t* __restrict__ Thn,
    ushort_t* __restrict__ Tln, float* __restrict__ out,
    float alpha, float beta)
{
    __shared__ float ST[64][33];   // ST[f][row]
    __shared__ float WK[64][64];
    const int t = threadIdx.x;
    const int rb = blockIdx.x * 32;
    const size_t M1 = (size_t)NN * FF;

    {
        float4* wd = (float4*)&WK[0][0];
        const float4* ws = (const float4*)Wk;
#pragma unroll
        for (int j = 0; j < 4; ++j) wd[t * 4 + j] = ws[t * 4 + j];
    }

    const int row = t >> 3;             // 0..31
    const int c0 = (t & 7) * 8;
    const size_t o = (size_t)(rb + row) * FF + c0;

    // phase A: t = alpha*sum(P) + beta*Tsub -> ST (transposed) [+ Tstore]
    {
        float tv[8];
#pragma unroll
        for (int half = 0; half < 2; ++half) {
            const size_t oo = o + 4 * half;
            float4 a0 = *(const float4*)(P + oo);
            const float4 a1 = *(const float4*)(P + M1 + oo);
            const float4 a2 = *(const float4*)(P + 2 * M1 + oo);
            const float4 a3 = *(const float4*)(P + 3 * M1 + oo);
            a0.x += a1.x + a2.x + a3.x; a0.y += a1.y + a2.y + a3.y;
            a0.z += a1.z + a2.z + a3.z; a0.w += a1.w + a2.w + a3.w;
            tv[4 * half + 0] = alpha * a0.x; tv[4 * half + 1] = alpha * a0.y;
            tv[4 * half + 2] = alpha * a0.z; tv[4 * half + 3] = alpha * a0.w;
        }
        if (beta != 0.f) {
            const float4 s0 = *(const float4*)(Tsub + o);
            const float4 s1 = *(const float4*)(Tsub + o + 4);
            tv[0] += beta * s0.x; tv[1] += beta * s0.y;
            tv[2] += beta * s0.z; tv[3] += beta * s0.w;
            tv[4] += beta * s1.x; tv[5] += beta * s1.y;
            tv[6] += beta * s1.z; tv[7] += beta * s1.w;
        }
        if (Tstore) {
            float4 v0, v1;
            v0.x = tv[0]; v0.y = tv[1]; v0.z = tv[2]; v0.w = tv[3];
            v1.x = tv[4]; v1.y = tv[5]; v1.z = tv[6]; v1.w = tv[7];
            *(float4*)(Tstore + o) = v0;
            *(float4*)(Tstore + o + 4) = v1;
        }
#pragma unroll
        for (int j = 0; j < 8; ++j) ST[c0 + j][row] = tv[j];
    }
    __syncthreads();

    // phase B: split-transpose -> Thn/Tln ([64][N] layout for global_load_lds)
    if (Thn) {
        const int f = t >> 2;           // 0..63
        const int r0 = (t & 3) * 8;     // 0,8,16,24
        ushort_t hh[8], ll[8];
#pragma unroll
        for (int i = 0; i < 8; ++i) f32_split(ST[f][r0 + i], hh[i], ll[i]);
        unsigned wh[4], wl[4];
#pragma unroll
        for (int j = 0; j < 4; ++j) {
            wh[j] = (unsigned)hh[2 * j] | ((unsigned)hh[2 * j + 1] << 16);
            wl[j] = (unsigned)ll[2 * j] | ((unsigned)ll[2 * j + 1] << 16);
        }
        const size_t ob = (size_t)f * NN + rb + r0;
        *(uint4*)(Thn + ob) = make_uint4(wh[0], wh[1], wh[2], wh[3]);
        *(uint4*)(Tln + ob) = make_uint4(wl[0], wl[1], wl[2], wl[3]);
    }

    // phase C: out += t @ Wk
    {
        float4 a0 = *(const float4*)(out + o);
        float4 a1 = *(const float4*)(out + o + 4);
#pragma unroll
        for (int f = 0; f < FF; ++f) {
            const float sv = ST[f][row];
            const float4 w0 = *(const float4*)&WK[f][c0];
            const float4 w1 = *(const float4*)&WK[f][c0 + 4];
            a0.x += sv * w0.x; a0.y += sv * w0.y;
            a0.z += sv * w0.z; a0.w += sv * w0.w;
            a1.x += sv * w1.x; a1.y += sv * w1.y;
            a1.z += sv * w1.z; a1.w += sv * w1.w;
        }
        *(float4*)(out + o) = a0;
        *(float4*)(out + o + 4) = a1;
    }
}

extern "C" void kernel_launch(void* const* d_in, const int* in_sizes, int n_in,
                              void* d_out, int out_size, void* d_ws, size_t ws_size,
                              hipStream_t stream)
{
    const float* x    = (const float*)d_in[0];
    const float* L    = (const float*)d_in[1];
    const float* W    = (const float*)d_in[2];   // (4, 64, 64)
    const float* bias = (const float*)d_in[3];
    float* out = (float*)d_out;

    const size_t M1 = (size_t)NN * FF;           // 1,048,576 elems
    float* wsf = (float*)d_ws;
    float* T1 = wsf;                             // 4 MB
    float* P  = wsf + M1;                        // 4 partials, 16 MB
    ushort_t* ThA = (ushort_t*)(wsf + 5 * M1);   // 2 MB each
    ushort_t* TlA = ThA + M1;
    ushort_t* ThB = TlA + M1;
    ushort_t* TlB = ThB + M1;

    const dim3 gc(NN / 64), bc(256);             // convT_init: 256 blocks
    const dim3 gg(SK * 256), bg(256);            // gemm: 1024 blocks
    const dim3 gp(NN / 32), bp(256);             // post_hop: 512 blocks

    // hop 0: ThA/TlA = splitT(x) ; out = bias + x@W0
    convT_init<<<gc, bc, 0, stream>>>(x, ThA, TlA, W + 0 * FF * FF, bias, out);
    // hop 1: T1 = L@x ; ThB/TlB = splitT(T1) ; out += T1@W1
    cheb_gemm_mfma<<<gg, bg, 0, stream>>>(L, ThA, TlA, P);
    post_hop<<<gp, bp, 0, stream>>>(P, x, W + 1 * FF * FF,
                                    T1, ThB, TlB, out, 1.f, 0.f);
    // hop 2: T2 = 2*(L@T1) - x ; ThA/TlA = splitT(T2) ; out += T2@W2
    cheb_gemm_mfma<<<gg, bg, 0, stream>>>(L, ThB, TlB, P);
    post_hop<<<gp, bp, 0, stream>>>(P, x, W + 2 * FF * FF,
                                    nullptr, ThA, TlA, out, 2.f, -1.f);
    // hop 3: T3 = 2*(L@T2) - T1 ; out += T3@W3
    cheb_gemm_mfma<<<gg, bg, 0, stream>>>(L, ThA, TlA, P);
    post_hop<<<gp, bp, 0, stream>>>(P, T1, W + 3 * FF * FF,
                                    nullptr, nullptr, nullptr, out, 2.f, -1.f);
}

// Round 11
// 688.327 us; speedup vs baseline: 1.1231x; 1.1096x over previous
//
#include <hip/hip_runtime.h>
#include <cstddef>
#include <cstdint>

#define NN 16384
#define FF 64
#define BM 64
#define BK 64
#define SK 4
#define KQ (NN / SK)        // 4096 k per split-K slice
#define NC (KQ / BK)        // 64 chunks per block (multiple of 4)

typedef __attribute__((ext_vector_type(8))) short bf16x8;
typedef __attribute__((ext_vector_type(4))) float f32x4;
typedef unsigned short ushort_t;

#define GLOBAL_AS __attribute__((address_space(1)))
#define LDS_AS    __attribute__((address_space(3)))

// truncate-split: f = hi + lo (+ ~2^-16 rel dropped); hi/lo as bf16 bit patterns
__device__ __forceinline__ void f32_split(float f, ushort_t& h, ushort_t& l) {
    unsigned u = __builtin_bit_cast(unsigned, f);
    h = (ushort_t)(u >> 16);
    float hf = __builtin_bit_cast(float, u & 0xFFFF0000u);
    float lo = f - hf;                       // exact (Sterbenz)
    l = (ushort_t)(__builtin_bit_cast(unsigned, lo) >> 16);
}

// ---------------------------------------------------------------------------
// Hop 0: Th/Tl = splitT(x) ; out = bias + x @ W0.   grid 256, 64 rows/block.
// ---------------------------------------------------------------------------
__global__ __launch_bounds__(256) void convT_init(
    const float* __restrict__ X, ushort_t* __restrict__ Th,
    ushort_t* __restrict__ Tl, const float* __restrict__ W0,
    const float* __restrict__ bias, float* __restrict__ out)
{
    __shared__ float S[64][68];
    __shared__ float W[64][64];
    const int t = threadIdx.x;
    const int rb = blockIdx.x * 64;
    {
        const int row = t >> 2;
        const int c0 = (t & 3) * 16;
        const float* src = X + (size_t)(rb + row) * FF + c0;
        *(float4*)&S[row][c0 + 0]  = *(const float4*)(src + 0);
        *(float4*)&S[row][c0 + 4]  = *(const float4*)(src + 4);
        *(float4*)&S[row][c0 + 8]  = *(const float4*)(src + 8);
        *(float4*)&S[row][c0 + 12] = *(const float4*)(src + 12);
        float4* wd = (float4*)&W[0][0];
        const float4* ws = (const float4*)W0;
#pragma unroll
        for (int j = 0; j < 4; ++j) wd[t * 4 + j] = ws[t * 4 + j];
    }
    __syncthreads();
    // split-transpose
    {
        const int cc = t >> 2;
        const int r0 = (t & 3) * 16;
        ushort_t hh[16], ll[16];
#pragma unroll
        for (int i = 0; i < 16; ++i) f32_split(S[r0 + i][cc], hh[i], ll[i]);
        unsigned wh[8], wl[8];
#pragma unroll
        for (int j = 0; j < 8; ++j) {
            wh[j] = (unsigned)hh[2 * j] | ((unsigned)hh[2 * j + 1] << 16);
            wl[j] = (unsigned)ll[2 * j] | ((unsigned)ll[2 * j + 1] << 16);
        }
        const size_t o = (size_t)cc * NN + rb + r0;
        *(uint4*)(Th + o)     = make_uint4(wh[0], wh[1], wh[2], wh[3]);
        *(uint4*)(Th + o + 8) = make_uint4(wh[4], wh[5], wh[6], wh[7]);
        *(uint4*)(Tl + o)     = make_uint4(wl[0], wl[1], wl[2], wl[3]);
        *(uint4*)(Tl + o + 8) = make_uint4(wl[4], wl[5], wl[6], wl[7]);
    }
    // out = bias + x@W0 : 2 rows x 8 cols per thread
    {
        const int row0 = (t >> 3) * 2;
        const int col0 = (t & 7) * 8;
        float acc[2][8];
        const float4 b0 = *(const float4*)(bias + col0);
        const float4 b1 = *(const float4*)(bias + col0 + 4);
#pragma unroll
        for (int r = 0; r < 2; ++r) {
            acc[r][0] = b0.x; acc[r][1] = b0.y; acc[r][2] = b0.z; acc[r][3] = b0.w;
            acc[r][4] = b1.x; acc[r][5] = b1.y; acc[r][6] = b1.z; acc[r][7] = b1.w;
        }
#pragma unroll
        for (int f = 0; f < FF; ++f) {
            const float x0 = S[row0][f];
            const float x1 = S[row0 + 1][f];
            const float4 w0 = *(const float4*)&W[f][col0];
            const float4 w1 = *(const float4*)&W[f][col0 + 4];
            acc[0][0] += x0 * w0.x; acc[0][1] += x0 * w0.y;
            acc[0][2] += x0 * w0.z; acc[0][3] += x0 * w0.w;
            acc[0][4] += x0 * w1.x; acc[0][5] += x0 * w1.y;
            acc[0][6] += x0 * w1.z; acc[0][7] += x0 * w1.w;
            acc[1][0] += x1 * w0.x; acc[1][1] += x1 * w0.y;
            acc[1][2] += x1 * w0.z; acc[1][3] += x1 * w0.w;
            acc[1][4] += x1 * w1.x; acc[1][5] += x1 * w1.y;
            acc[1][6] += x1 * w1.z; acc[1][7] += x1 * w1.w;
        }
#pragma unroll
        for (int r = 0; r < 2; ++r) {
            const size_t o = (size_t)(rb + row0 + r) * FF + col0;
            float4 v0, v1;
            v0.x = acc[r][0]; v0.y = acc[r][1]; v0.z = acc[r][2]; v0.w = acc[r][3];
            v1.x = acc[r][4]; v1.y = acc[r][5]; v1.z = acc[r][6]; v1.w = acc[r][7];
            *(float4*)(out + o) = v0;
            *(float4*)(out + o + 4) = v1;
        }
    }
}

// ---------------------------------------------------------------------------
// P[s] = L[:, kslice_s] @ T[kslice_s, :]   via bf16 hi/lo-split MFMA.
// grid SK*256: s = bx>>8, m = bx&255. 256 thr = 4 waves (2x2 of 32x32 tiles).
// Identical to the 726-us best EXCEPT: A loads issued in 2-chunk pairs so
// each L row is visited with a 512B contiguous burst (vs 256B) -- halves
// DRAM bank-activation rate for the A stream. Byte counts unchanged.
// ---------------------------------------------------------------------------
__global__ __launch_bounds__(256) void cheb_gemm_mfma(
    const float* __restrict__ L, const ushort_t* __restrict__ Th,
    const ushort_t* __restrict__ Tl, float* __restrict__ P)
{
    __shared__ ushort_t Ah[2][BM * BK];
    __shared__ ushort_t Al[2][BM * BK];
    __shared__ ushort_t Bh[2][FF * BK];
    __shared__ ushort_t Bl[2][FF * BK];

    const int tid  = threadIdx.x;
    const int lane = tid & 63;
    const int w    = tid >> 6;
    const int s    = blockIdx.x >> 8;
    const int m    = blockIdx.x & 255;
    const int row0g = m * BM;
    const int kbase = s * KQ;

    const int wm = w >> 1, wn = w & 1;      // wave tile (32x32) coords
    const int frow = lane & 15;             // row (A) / col (B) within 16-tile
    const int fk8  = (lane >> 4) * 8;       // k-offset base

    // A staging: thread covers rows arow+16p, k = akq*4..+3
    const int arow = w * 4 + (lane >> 4);
    const int akq  = lane & 15;
    const int axor = (arow & 7) << 4;

    // B staging: wave picks hi/lo tile and 4 col-octets
    const ushort_t* Tsrc = (w & 1) ? Tl : Th;
    const int boct0 = (w >> 1) * 4;

    f32x4 acc[2][2];
#pragma unroll
    for (int i = 0; i < 2; ++i)
#pragma unroll
        for (int j = 0; j < 2; ++j) acc[i][j] = (f32x4)0.f;

    // Pair buffers: va[p*2 + j] = row-group p (arow+16p), chunk-in-pair j.
    float4 vaA[8], vaB[8];

    const float* Labase = L + (size_t)(row0g + arow) * NN + kbase + akq * 4;

#define ISSUE_B(c, slot)                                                        \
    {                                                                           \
        const size_t kc = (size_t)(c) * BK;                                     \
        char* bbase = (char*)((w & 1) ? Bl[slot] : Bh[slot]);                   \
        _Pragma("unroll")                                                       \
        for (int o = 0; o < 4; ++o) {                                           \
            const int oct = boct0 + o;                                          \
            const int col = oct * 8 + (lane >> 3);                              \
            const ushort_t* g = Tsrc + (size_t)col * NN + kbase + kc            \
                                + (((lane & 7) ^ (col & 7)) * 8);               \
            __builtin_amdgcn_global_load_lds((const GLOBAL_AS void*)g,          \
                (LDS_AS void*)(bbase + oct * 1024), 16, 0, 0);                  \
        }                                                                       \
    }

// load chunks c and c+1 for all 4 row-groups; per-row the two 16B loads are
// adjacent 256B segments -> 512B contiguous per row visit
#define LOAD_PAIR(va, c)                                                        \
    {                                                                           \
        const float* g = Labase + (size_t)(c) * BK;                             \
        va[0] = *(const float4*)(g);                                            \
        va[1] = *(const float4*)(g + BK);                                       \
        va[2] = *(const float4*)(g + (size_t)16 * NN);                          \
        va[3] = *(const float4*)(g + (size_t)16 * NN + BK);                     \
        va[4] = *(const float4*)(g + (size_t)32 * NN);                          \
        va[5] = *(const float4*)(g + (size_t)32 * NN + BK);                     \
        va[6] = *(const float4*)(g + (size_t)48 * NN);                          \
        va[7] = *(const float4*)(g + (size_t)48 * NN + BK);                     \
    }

// write chunk-in-pair j of buffer va into LDS slot
#define CONV_WRITE_A(va, j, slot)                                               \
    {                                                                           \
        char* ahb = (char*)Ah[slot];                                            \
        char* alb = (char*)Al[slot];                                            \
        _Pragma("unroll")                                                       \
        for (int p = 0; p < 4; ++p) {                                           \
            const float4 v = va[p * 2 + (j)];                                   \
            const int r = arow + p * 16;                                        \
            ushort_t h0, h1, h2, h3, l0, l1, l2, l3;                            \
            f32_split(v.x, h0, l0);                                             \
            f32_split(v.y, h1, l1);                                             \
            f32_split(v.z, h2, l2);                                             \
            f32_split(v.w, h3, l3);                                             \
            const unsigned hi01 = (unsigned)h0 | ((unsigned)h1 << 16);          \
            const unsigned hi23 = (unsigned)h2 | ((unsigned)h3 << 16);          \
            const unsigned lo01 = (unsigned)l0 | ((unsigned)l1 << 16);          \
            const unsigned lo23 = (unsigned)l2 | ((unsigned)l3 << 16);          \
            const int byte = (r * 128 + akq * 8) ^ axor;                        \
            *(uint2*)(ahb + byte) = make_uint2(hi01, hi23);                     \
            *(uint2*)(alb + byte) = make_uint2(lo01, lo23);                     \
        }                                                                       \
    }

#define COMPUTE(slot)                                                           \
    {                                                                           \
        const char* ahb = (const char*)Ah[slot];                                \
        const char* alb = (const char*)Al[slot];                                \
        const char* bhb = (const char*)Bh[slot];                                \
        const char* blb = (const char*)Bl[slot];                                \
        _Pragma("unroll")                                                       \
        for (int ks = 0; ks < 2; ++ks) {                                        \
            const int kk = ks * 32 + fk8;                                       \
            bf16x8 Afh[2], Afl[2], Bfh[2], Bfl[2];                              \
            _Pragma("unroll")                                                   \
            for (int mt = 0; mt < 2; ++mt) {                                    \
                const int row = wm * 32 + mt * 16 + frow;                       \
                const int off = (row * 128 + kk * 2) ^ ((row & 7) << 4);        \
                Afh[mt] = *(const bf16x8*)(ahb + off);                          \
                Afl[mt] = *(const bf16x8*)(alb + off);                          \
            }                                                                   \
            _Pragma("unroll")                                                   \
            for (int nt = 0; nt < 2; ++nt) {                                    \
                const int col = wn * 32 + nt * 16 + frow;                       \
                const int off = (col * 128 + kk * 2) ^ ((col & 7) << 4);        \
                Bfh[nt] = *(const bf16x8*)(bhb + off);                          \
                Bfl[nt] = *(const bf16x8*)(blb + off);                          \
            }                                                                   \
            _Pragma("unroll")                                                   \
            for (int mt = 0; mt < 2; ++mt)                                      \
                _Pragma("unroll")                                               \
                for (int nt = 0; nt < 2; ++nt) {                                \
                    acc[mt][nt] = __builtin_amdgcn_mfma_f32_16x16x32_bf16(      \
                        Afh[mt], Bfh[nt], acc[mt][nt], 0, 0, 0);                \
                    acc[mt][nt] = __builtin_amdgcn_mfma_f32_16x16x32_bf16(      \
                        Afh[mt], Bfl[nt], acc[mt][nt], 0, 0, 0);                \
                    acc[mt][nt] = __builtin_amdgcn_mfma_f32_16x16x32_bf16(      \
                        Afl[mt], Bfh[nt], acc[mt][nt], 0, 0, 0);                \
                }                                                               \
        }                                                                       \
    }

    // ---- prologue: chunk 0 -> slot 0 (pair 0,1 loaded)
    ISSUE_B(0, 0)
    LOAD_PAIR(vaA, 0)
    CONV_WRITE_A(vaA, 0, 0)
    __syncthreads();

#pragma unroll 1
    for (int c = 0; c < NC; c += 4) {
        // chunk c (slot0); stage c+1
        ISSUE_B(c + 1, 1)
        if (c + 2 < NC) LOAD_PAIR(vaB, c + 2)
        COMPUTE(0)
        CONV_WRITE_A(vaA, 1, 1)
        __syncthreads();
        // chunk c+1 (slot1); stage c+2
        if (c + 2 < NC) ISSUE_B(c + 2, 0)
        COMPUTE(1)
        if (c + 2 < NC) CONV_WRITE_A(vaB, 0, 0)
        __syncthreads();
        if (c + 2 >= NC) break;
        // chunk c+2 (slot0); stage c+3
        ISSUE_B(c + 3, 1)
        if (c + 4 < NC) LOAD_PAIR(vaA, c + 4)
        COMPUTE(0)
        CONV_WRITE_A(vaB, 1, 1)
        __syncthreads();
        // chunk c+3 (slot1); stage c+4
        if (c + 4 < NC) ISSUE_B(c + 4, 0)
        COMPUTE(1)
        if (c + 4 < NC) CONV_WRITE_A(vaA, 0, 0)
        __syncthreads();
    }

    // ---- write partial: C/D layout col=lane&15, row=(lane>>4)*4+r  (m89)
    float* Pp = P + (size_t)s * NN * FF;
#pragma unroll
    for (int mt = 0; mt < 2; ++mt)
#pragma unroll
        for (int nt = 0; nt < 2; ++nt) {
            const int row = row0g + wm * 32 + mt * 16 + (lane >> 4) * 4;
            const int col = wn * 32 + nt * 16 + frow;
#pragma unroll
            for (int r = 0; r < 4; ++r)
                Pp[(size_t)(row + r) * FF + col] = acc[mt][nt][r];
        }
#undef ISSUE_B
#undef LOAD_PAIR
#undef CONV_WRITE_A
#undef COMPUTE
}

// ---------------------------------------------------------------------------
// Fused per-hop epilogue, 32 rows/block (grid 512):
//   t = alpha*(P0+P1+P2+P3) + beta*Tsub ; [Tstore]=t ; [Thn/Tln]=splitT(t) ;
//   out += t @ Wk
// ---------------------------------------------------------------------------
__global__ __launch_bounds__(256) void post_hop(
    const float* __restrict__ P,
    const float* __restrict__ Tsub, const float* __restrict__ Wk,
    float* __restrict__ Tstore, ushort_t* __restrict__ Thn,
    ushort_t* __restrict__ Tln, float* __restrict__ out,
    float alpha, float beta)
{
    __shared__ float ST[64][33];   // ST[f][row]
    __shared__ float WK[64][64];
    const int t = threadIdx.x;
    const int rb = blockIdx.x * 32;
    const size_t M1 = (size_t)NN * FF;

    {
        float4* wd = (float4*)&WK[0][0];
        const float4* ws = (const float4*)Wk;
#pragma unroll
        for (int j = 0; j < 4; ++j) wd[t * 4 + j] = ws[t * 4 + j];
    }

    const int row = t >> 3;             // 0..31
    const int c0 = (t & 7) * 8;
    const size_t o = (size_t)(rb + row) * FF + c0;

    // phase A: t = alpha*sum(P) + beta*Tsub -> ST (transposed) [+ Tstore]
    {
        float tv[8];
#pragma unroll
        for (int half = 0; half < 2; ++half) {
            const size_t oo = o + 4 * half;
            float4 a0 = *(const float4*)(P + oo);
            const float4 a1 = *(const float4*)(P + M1 + oo);
            const float4 a2 = *(const float4*)(P + 2 * M1 + oo);
            const float4 a3 = *(const float4*)(P + 3 * M1 + oo);
            a0.x += a1.x + a2.x + a3.x; a0.y += a1.y + a2.y + a3.y;
            a0.z += a1.z + a2.z + a3.z; a0.w += a1.w + a2.w + a3.w;
            tv[4 * half + 0] = alpha * a0.x; tv[4 * half + 1] = alpha * a0.y;
            tv[4 * half + 2] = alpha * a0.z; tv[4 * half + 3] = alpha * a0.w;
        }
        if (beta != 0.f) {
            const float4 s0 = *(const float4*)(Tsub + o);
            const float4 s1 = *(const float4*)(Tsub + o + 4);
            tv[0] += beta * s0.x; tv[1] += beta * s0.y;
            tv[2] += beta * s0.z; tv[3] += beta * s0.w;
            tv[4] += beta * s1.x; tv[5] += beta * s1.y;
            tv[6] += beta * s1.z; tv[7] += beta * s1.w;
        }
        if (Tstore) {
            float4 v0, v1;
            v0.x = tv[0]; v0.y = tv[1]; v0.z = tv[2]; v0.w = tv[3];
            v1.x = tv[4]; v1.y = tv[5]; v1.z = tv[6]; v1.w = tv[7];
            *(float4*)(Tstore + o) = v0;
            *(float4*)(Tstore + o + 4) = v1;
        }
#pragma unroll
        for (int j = 0; j < 8; ++j) ST[c0 + j][row] = tv[j];
    }
    __syncthreads();

    // phase B: split-transpose -> Thn/Tln ([64][N] layout for global_load_lds)
    if (Thn) {
        const int f = t >> 2;           // 0..63
        const int r0 = (t & 3) * 8;     // 0,8,16,24
        ushort_t hh[8], ll[8];
#pragma unroll
        for (int i = 0; i < 8; ++i) f32_split(ST[f][r0 + i], hh[i], ll[i]);
        unsigned wh[4], wl[4];
#pragma unroll
        for (int j = 0; j < 4; ++j) {
            wh[j] = (unsigned)hh[2 * j] | ((unsigned)hh[2 * j + 1] << 16);
            wl[j] = (unsigned)ll[2 * j] | ((unsigned)ll[2 * j + 1] << 16);
        }
        const size_t ob = (size_t)f * NN + rb + r0;
        *(uint4*)(Thn + ob) = make_uint4(wh[0], wh[1], wh[2], wh[3]);
        *(uint4*)(Tln + ob) = make_uint4(wl[0], wl[1], wl[2], wl[3]);
    }

    // phase C: out += t @ Wk
    {
        float4 a0 = *(const float4*)(out + o);
        float4 a1 = *(const float4*)(out + o + 4);
#pragma unroll
        for (int f = 0; f < FF; ++f) {
            const float sv = ST[f][row];
            const float4 w0 = *(const float4*)&WK[f][c0];
            const float4 w1 = *(const float4*)&WK[f][c0 + 4];
            a0.x += sv * w0.x; a0.y += sv * w0.y;
            a0.z += sv * w0.z; a0.w += sv * w0.w;
            a1.x += sv * w1.x; a1.y += sv * w1.y;
            a1.z += sv * w1.z; a1.w += sv * w1.w;
        }
        *(float4*)(out + o) = a0;
        *(float4*)(out + o + 4) = a1;
    }
}

extern "C" void kernel_launch(void* const* d_in, const int* in_sizes, int n_in,
                              void* d_out, int out_size, void* d_ws, size_t ws_size,
                              hipStream_t stream)
{
    const float* x    = (const float*)d_in[0];
    const float* L    = (const float*)d_in[1];
    const float* W    = (const float*)d_in[2];   // (4, 64, 64)
    const float* bias = (const float*)d_in[3];
    float* out = (float*)d_out;

    const size_t M1 = (size_t)NN * FF;           // 1,048,576 elems
    float* wsf = (float*)d_ws;
    float* T1 = wsf;                             // 4 MB
    float* P  = wsf + M1;                        // 4 partials, 16 MB
    ushort_t* ThA = (ushort_t*)(wsf + 5 * M1);   // 2 MB each
    ushort_t* TlA = ThA + M1;
    ushort_t* ThB = TlA + M1;
    ushort_t* TlB = ThB + M1;

    const dim3 gc(NN / 64), bc(256);             // convT_init: 256 blocks
    const dim3 gg(SK * 256), bg(256);            // gemm: 1024 blocks
    const dim3 gp(NN / 32), bp(256);             // post_hop: 512 blocks

    // hop 0: ThA/TlA = splitT(x) ; out = bias + x@W0
    convT_init<<<gc, bc, 0, stream>>>(x, ThA, TlA, W + 0 * FF * FF, bias, out);
    // hop 1: T1 = L@x ; ThB/TlB = splitT(T1) ; out += T1@W1
    cheb_gemm_mfma<<<gg, bg, 0, stream>>>(L, ThA, TlA, P);
    post_hop<<<gp, bp, 0, stream>>>(P, x, W + 1 * FF * FF,
                                    T1, ThB, TlB, out, 1.f, 0.f);
    // hop 2: T2 = 2*(L@T1) - x ; ThA/TlA = splitT(T2) ; out += T2@W2
    cheb_gemm_mfma<<<gg, bg, 0, stream>>>(L, ThB, TlB, P);
    post_hop<<<gp, bp, 0, stream>>>(P, x, W + 2 * FF * FF,
                                    nullptr, ThA, TlA, out, 2.f, -1.f);
    // hop 3: T3 = 2*(L@T2) - T1 ; out += T3@W3
    cheb_gemm_mfma<<<gg, bg, 0, stream>>>(L, ThA, TlA, P);
    post_hop<<<gp, bp, 0, stream>>>(P, T1, W + 3 * FF * FF,
                                    nullptr, nullptr, nullptr, out, 2.f, -1.f);
}

// Round 12
// 688.281 us; speedup vs baseline: 1.1232x; 1.0001x over previous
//
#include <hip/hip_runtime.h>
#include <cstddef>
#include <cstdint>

#define NN 16384
#define FF 64
#define BM 64
#define BK 64
#define SK 4
#define KQ (NN / SK)        // 4096 k per split-K slice
#define NC (KQ / BK)        // 64 chunks per block (multiple of 8)

typedef __attribute__((ext_vector_type(8))) short bf16x8;
typedef __attribute__((ext_vector_type(4))) float f32x4;
typedef unsigned short ushort_t;

#define GLOBAL_AS __attribute__((address_space(1)))
#define LDS_AS    __attribute__((address_space(3)))

// truncate-split: f = hi + lo (+ ~2^-16 rel dropped); hi/lo as bf16 bit patterns
__device__ __forceinline__ void f32_split(float f, ushort_t& h, ushort_t& l) {
    unsigned u = __builtin_bit_cast(unsigned, f);
    h = (ushort_t)(u >> 16);
    float hf = __builtin_bit_cast(float, u & 0xFFFF0000u);
    float lo = f - hf;                       // exact (Sterbenz)
    l = (ushort_t)(__builtin_bit_cast(unsigned, lo) >> 16);
}

// ---------------------------------------------------------------------------
// Hop 0: Th/Tl = splitT(x) ; out = bias + x @ W0.   grid 256, 64 rows/block.
// ---------------------------------------------------------------------------
__global__ __launch_bounds__(256) void convT_init(
    const float* __restrict__ X, ushort_t* __restrict__ Th,
    ushort_t* __restrict__ Tl, const float* __restrict__ W0,
    const float* __restrict__ bias, float* __restrict__ out)
{
    __shared__ float S[64][68];
    __shared__ float W[64][64];
    const int t = threadIdx.x;
    const int rb = blockIdx.x * 64;
    {
        const int row = t >> 2;
        const int c0 = (t & 3) * 16;
        const float* src = X + (size_t)(rb + row) * FF + c0;
        *(float4*)&S[row][c0 + 0]  = *(const float4*)(src + 0);
        *(float4*)&S[row][c0 + 4]  = *(const float4*)(src + 4);
        *(float4*)&S[row][c0 + 8]  = *(const float4*)(src + 8);
        *(float4*)&S[row][c0 + 12] = *(const float4*)(src + 12);
        float4* wd = (float4*)&W[0][0];
        const float4* ws = (const float4*)W0;
#pragma unroll
        for (int j = 0; j < 4; ++j) wd[t * 4 + j] = ws[t * 4 + j];
    }
    __syncthreads();
    // split-transpose
    {
        const int cc = t >> 2;
        const int r0 = (t & 3) * 16;
        ushort_t hh[16], ll[16];
#pragma unroll
        for (int i = 0; i < 16; ++i) f32_split(S[r0 + i][cc], hh[i], ll[i]);
        unsigned wh[8], wl[8];
#pragma unroll
        for (int j = 0; j < 8; ++j) {
            wh[j] = (unsigned)hh[2 * j] | ((unsigned)hh[2 * j + 1] << 16);
            wl[j] = (unsigned)ll[2 * j] | ((unsigned)ll[2 * j + 1] << 16);
        }
        const size_t o = (size_t)cc * NN + rb + r0;
        *(uint4*)(Th + o)     = make_uint4(wh[0], wh[1], wh[2], wh[3]);
        *(uint4*)(Th + o + 8) = make_uint4(wh[4], wh[5], wh[6], wh[7]);
        *(uint4*)(Tl + o)     = make_uint4(wl[0], wl[1], wl[2], wl[3]);
        *(uint4*)(Tl + o + 8) = make_uint4(wl[4], wl[5], wl[6], wl[7]);
    }
    // out = bias + x@W0 : 2 rows x 8 cols per thread
    {
        const int row0 = (t >> 3) * 2;
        const int col0 = (t & 7) * 8;
        float acc[2][8];
        const float4 b0 = *(const float4*)(bias + col0);
        const float4 b1 = *(const float4*)(bias + col0 + 4);
#pragma unroll
        for (int r = 0; r < 2; ++r) {
            acc[r][0] = b0.x; acc[r][1] = b0.y; acc[r][2] = b0.z; acc[r][3] = b0.w;
            acc[r][4] = b1.x; acc[r][5] = b1.y; acc[r][6] = b1.z; acc[r][7] = b1.w;
        }
#pragma unroll
        for (int f = 0; f < FF; ++f) {
            const float x0 = S[row0][f];
            const float x1 = S[row0 + 1][f];
            const float4 w0 = *(const float4*)&W[f][col0];
            const float4 w1 = *(const float4*)&W[f][col0 + 4];
            acc[0][0] += x0 * w0.x; acc[0][1] += x0 * w0.y;
            acc[0][2] += x0 * w0.z; acc[0][3] += x0 * w0.w;
            acc[0][4] += x0 * w1.x; acc[0][5] += x0 * w1.y;
            acc[0][6] += x0 * w1.z; acc[0][7] += x0 * w1.w;
            acc[1][0] += x1 * w0.x; acc[1][1] += x1 * w0.y;
            acc[1][2] += x1 * w0.z; acc[1][3] += x1 * w0.w;
            acc[1][4] += x1 * w1.x; acc[1][5] += x1 * w1.y;
            acc[1][6] += x1 * w1.z; acc[1][7] += x1 * w1.w;
        }
#pragma unroll
        for (int r = 0; r < 2; ++r) {
            const size_t o = (size_t)(rb + row0 + r) * FF + col0;
            float4 v0, v1;
            v0.x = acc[r][0]; v0.y = acc[r][1]; v0.z = acc[r][2]; v0.w = acc[r][3];
            v1.x = acc[r][4]; v1.y = acc[r][5]; v1.z = acc[r][6]; v1.w = acc[r][7];
            *(float4*)(out + o) = v0;
            *(float4*)(out + o + 4) = v1;
        }
    }
}

// ---------------------------------------------------------------------------
// P[s] = L[:, kslice_s] @ T[kslice_s, :]   via bf16 hi/lo-split MFMA.
// grid SK*256: s = bx>>8, m = bx&255. 256 thr = 4 waves (2x2 of 32x32 tiles).
// R11 + 4-chunk A superchunks: each L row visited with a 1024B contiguous
// burst (vs 512B). va double-buffer = 2x16 float4 (128 VGPR);
// __launch_bounds__(256,2) matches the real 2-blocks/CU occupancy.
// ---------------------------------------------------------------------------
__global__ __launch_bounds__(256, 2) void cheb_gemm_mfma(
    const float* __restrict__ L, const ushort_t* __restrict__ Th,
    const ushort_t* __restrict__ Tl, float* __restrict__ P)
{
    __shared__ ushort_t Ah[2][BM * BK];
    __shared__ ushort_t Al[2][BM * BK];
    __shared__ ushort_t Bh[2][FF * BK];
    __shared__ ushort_t Bl[2][FF * BK];

    const int tid  = threadIdx.x;
    const int lane = tid & 63;
    const int w    = tid >> 6;
    const int s    = blockIdx.x >> 8;
    const int m    = blockIdx.x & 255;
    const int row0g = m * BM;
    const int kbase = s * KQ;

    const int wm = w >> 1, wn = w & 1;      // wave tile (32x32) coords
    const int frow = lane & 15;             // row (A) / col (B) within 16-tile
    const int fk8  = (lane >> 4) * 8;       // k-offset base

    // A staging: thread covers rows arow+16p, k = akq*4..+3
    const int arow = w * 4 + (lane >> 4);
    const int akq  = lane & 15;
    const int axor = (arow & 7) << 4;

    // B staging: wave picks hi/lo tile and 4 col-octets
    const ushort_t* Tsrc = (w & 1) ? Tl : Th;
    const int boct0 = (w >> 1) * 4;

    f32x4 acc[2][2];
#pragma unroll
    for (int i = 0; i < 2; ++i)
#pragma unroll
        for (int j = 0; j < 2; ++j) acc[i][j] = (f32x4)0.f;

    // Superchunk buffers: va[p*4 + j] = row-group p (arow+16p), chunk-in-quad j
    float4 vaA[16], vaB[16];

    const float* Labase = L + (size_t)(row0g + arow) * NN + kbase + akq * 4;

#define ISSUE_B(c, slot)                                                        \
    {                                                                           \
        const size_t kc = (size_t)(c) * BK;                                     \
        char* bbase = (char*)((w & 1) ? Bl[slot] : Bh[slot]);                   \
        _Pragma("unroll")                                                       \
        for (int o = 0; o < 4; ++o) {                                           \
            const int oct = boct0 + o;                                          \
            const int col = oct * 8 + (lane >> 3);                              \
            const ushort_t* g = Tsrc + (size_t)col * NN + kbase + kc            \
                                + (((lane & 7) ^ (col & 7)) * 8);               \
            __builtin_amdgcn_global_load_lds((const GLOBAL_AS void*)g,          \
                (LDS_AS void*)(bbase + oct * 1024), 16, 0, 0);                  \
        }                                                                       \
    }

// load chunks c..c+3 for all 4 row-groups; per row the four 16B loads are
// adjacent 256B segments -> 1024B contiguous per row visit
#define LOAD_QUAD(va, c)                                                        \
    {                                                                           \
        const float* g = Labase + (size_t)(c) * BK;                             \
        _Pragma("unroll")                                                       \
        for (int p = 0; p < 4; ++p) {                                           \
            const float* gr = g + (size_t)(p * 16) * NN;                        \
            va[p * 4 + 0] = *(const float4*)(gr);                               \
            va[p * 4 + 1] = *(const float4*)(gr + BK);                          \
            va[p * 4 + 2] = *(const float4*)(gr + 2 * BK);                      \
            va[p * 4 + 3] = *(const float4*)(gr + 3 * BK);                      \
        }                                                                       \
    }

// write chunk-in-quad j of buffer va into LDS slot
#define CONV_WRITE_A(va, j, slot)                                               \
    {                                                                           \
        char* ahb = (char*)Ah[slot];                                            \
        char* alb = (char*)Al[slot];                                            \
        _Pragma("unroll")                                                       \
        for (int p = 0; p < 4; ++p) {                                           \
            const float4 v = va[p * 4 + (j)];                                   \
            const int r = arow + p * 16;                                        \
            ushort_t h0, h1, h2, h3, l0, l1, l2, l3;                            \
            f32_split(v.x, h0, l0);                                             \
            f32_split(v.y, h1, l1);                                             \
            f32_split(v.z, h2, l2);                                             \
            f32_split(v.w, h3, l3);                                             \
            const unsigned hi01 = (unsigned)h0 | ((unsigned)h1 << 16);          \
            const unsigned hi23 = (unsigned)h2 | ((unsigned)h3 << 16);          \
            const unsigned lo01 = (unsigned)l0 | ((unsigned)l1 << 16);          \
            const unsigned lo23 = (unsigned)l2 | ((unsigned)l3 << 16);          \
            const int byte = (r * 128 + akq * 8) ^ axor;                        \
            *(uint2*)(ahb + byte) = make_uint2(hi01, hi23);                     \
            *(uint2*)(alb + byte) = make_uint2(lo01, lo23);                     \
        }                                                                       \
    }

#define COMPUTE(slot)                                                           \
    {                                                                           \
        const char* ahb = (const char*)Ah[slot];                                \
        const char* alb = (const char*)Al[slot];                                \
        const char* bhb = (const char*)Bh[slot];                                \
        const char* blb = (const char*)Bl[slot];                                \
        _Pragma("unroll")                                                       \
        for (int ks = 0; ks < 2; ++ks) {                                        \
            const int kk = ks * 32 + fk8;                                       \
            bf16x8 Afh[2], Afl[2], Bfh[2], Bfl[2];                              \
            _Pragma("unroll")                                                   \
            for (int mt = 0; mt < 2; ++mt) {                                    \
                const int row = wm * 32 + mt * 16 + frow;                       \
                const int off = (row * 128 + kk * 2) ^ ((row & 7) << 4);        \
                Afh[mt] = *(const bf16x8*)(ahb + off);                          \
                Afl[mt] = *(const bf16x8*)(alb + off);                          \
            }                                                                   \
            _Pragma("unroll")                                                   \
            for (int nt = 0; nt < 2; ++nt) {                                    \
                const int col = wn * 32 + nt * 16 + frow;                       \
                const int off = (col * 128 + kk * 2) ^ ((col & 7) << 4);        \
                Bfh[nt] = *(const bf16x8*)(bhb + off);                          \
                Bfl[nt] = *(const bf16x8*)(blb + off);                          \
            }                                                                   \
            _Pragma("unroll")                                                   \
            for (int mt = 0; mt < 2; ++mt)                                      \
                _Pragma("unroll")                                               \
                for (int nt = 0; nt < 2; ++nt) {                                \
                    acc[mt][nt] = __builtin_amdgcn_mfma_f32_16x16x32_bf16(      \
                        Afh[mt], Bfh[nt], acc[mt][nt], 0, 0, 0);                \
                    acc[mt][nt] = __builtin_amdgcn_mfma_f32_16x16x32_bf16(      \
                        Afh[mt], Bfl[nt], acc[mt][nt], 0, 0, 0);                \
                    acc[mt][nt] = __builtin_amdgcn_mfma_f32_16x16x32_bf16(      \
                        Afl[mt], Bfh[nt], acc[mt][nt], 0, 0, 0);                \
                }                                                               \
        }                                                                       \
    }

    // ---- prologue: superchunk 0 (chunks 0-3) -> vaA; chunk 0 staged
    ISSUE_B(0, 0)
    LOAD_QUAD(vaA, 0)
    CONV_WRITE_A(vaA, 0, 0)
    __syncthreads();

#pragma unroll 1
    for (int c = 0; c < NC; c += 8) {
        // ---- superchunk from vaA: chunks c..c+3; prefetch c+4..c+7 -> vaB
        ISSUE_B(c + 1, 1)
        LOAD_QUAD(vaB, c + 4)
        COMPUTE(0)
        CONV_WRITE_A(vaA, 1, 1)
        __syncthreads();

        ISSUE_B(c + 2, 0)
        COMPUTE(1)
        CONV_WRITE_A(vaA, 2, 0)
        __syncthreads();

        ISSUE_B(c + 3, 1)
        COMPUTE(0)
        CONV_WRITE_A(vaA, 3, 1)
        __syncthreads();

        ISSUE_B(c + 4, 0)
        COMPUTE(1)
        CONV_WRITE_A(vaB, 0, 0)
        __syncthreads();

        // ---- superchunk from vaB: chunks c+4..c+7; prefetch c+8.. -> vaA
        ISSUE_B(c + 5, 1)
        if (c + 8 < NC) LOAD_QUAD(vaA, c + 8)
        COMPUTE(0)
        CONV_WRITE_A(vaB, 1, 1)
        __syncthreads();

        ISSUE_B(c + 6, 0)
        COMPUTE(1)
        CONV_WRITE_A(vaB, 2, 0)
        __syncthreads();

        ISSUE_B(c + 7, 1)
        COMPUTE(0)
        CONV_WRITE_A(vaB, 3, 1)
        __syncthreads();

        if (c + 8 < NC) { ISSUE_B(c + 8, 0) }
        COMPUTE(1)
        if (c + 8 < NC) { CONV_WRITE_A(vaA, 0, 0) }
        __syncthreads();
    }

    // ---- write partial: C/D layout col=lane&15, row=(lane>>4)*4+r  (m89)
    float* Pp = P + (size_t)s * NN * FF;
#pragma unroll
    for (int mt = 0; mt < 2; ++mt)
#pragma unroll
        for (int nt = 0; nt < 2; ++nt) {
            const int row = row0g + wm * 32 + mt * 16 + (lane >> 4) * 4;
            const int col = wn * 32 + nt * 16 + frow;
#pragma unroll
            for (int r = 0; r < 4; ++r)
                Pp[(size_t)(row + r) * FF + col] = acc[mt][nt][r];
        }
#undef ISSUE_B
#undef LOAD_QUAD
#undef CONV_WRITE_A
#undef COMPUTE
}

// ---------------------------------------------------------------------------
// Fused per-hop epilogue, 32 rows/block (grid 512):
//   t = alpha*(P0+P1+P2+P3) + beta*Tsub ; [Tstore]=t ; [Thn/Tln]=splitT(t) ;
//   out += t @ Wk
// ---------------------------------------------------------------------------
__global__ __launch_bounds__(256) void post_hop(
    const float* __restrict__ P,
    const float* __restrict__ Tsub, const float* __restrict__ Wk,
    float* __restrict__ Tstore, ushort_t* __restrict__ Thn,
    ushort_t* __restrict__ Tln, float* __restrict__ out,
    float alpha, float beta)
{
    __shared__ float ST[64][33];   // ST[f][row]
    __shared__ float WK[64][64];
    const int t = threadIdx.x;
    const int rb = blockIdx.x * 32;
    const size_t M1 = (size_t)NN * FF;

    {
        float4* wd = (float4*)&WK[0][0];
        const float4* ws = (const float4*)Wk;
#pragma unroll
        for (int j = 0; j < 4; ++j) wd[t * 4 + j] = ws[t * 4 + j];
    }

    const int row = t >> 3;             // 0..31
    const int c0 = (t & 7) * 8;
    const size_t o = (size_t)(rb + row) * FF + c0;

    // phase A: t = alpha*sum(P) + beta*Tsub -> ST (transposed) [+ Tstore]
    {
        float tv[8];
#pragma unroll
        for (int half = 0; half < 2; ++half) {
            const size_t oo = o + 4 * half;
            float4 a0 = *(const float4*)(P + oo);
            const float4 a1 = *(const float4*)(P + M1 + oo);
            const float4 a2 = *(const float4*)(P + 2 * M1 + oo);
            const float4 a3 = *(const float4*)(P + 3 * M1 + oo);
            a0.x += a1.x + a2.x + a3.x; a0.y += a1.y + a2.y + a3.y;
            a0.z += a1.z + a2.z + a3.z; a0.w += a1.w + a2.w + a3.w;
            tv[4 * half + 0] = alpha * a0.x; tv[4 * half + 1] = alpha * a0.y;
            tv[4 * half + 2] = alpha * a0.z; tv[4 * half + 3] = alpha * a0.w;
        }
        if (beta != 0.f) {
            const float4 s0 = *(const float4*)(Tsub + o);
            const float4 s1 = *(const float4*)(Tsub + o + 4);
            tv[0] += beta * s0.x; tv[1] += beta * s0.y;
            tv[2] += beta * s0.z; tv[3] += beta * s0.w;
            tv[4] += beta * s1.x; tv[5] += beta * s1.y;
            tv[6] += beta * s1.z; tv[7] += beta * s1.w;
        }
        if (Tstore) {
            float4 v0, v1;
            v0.x = tv[0]; v0.y = tv[1]; v0.z = tv[2]; v0.w = tv[3];
            v1.x = tv[4]; v1.y = tv[5]; v1.z = tv[6]; v1.w = tv[7];
            *(float4*)(Tstore + o) = v0;
            *(float4*)(Tstore + o + 4) = v1;
        }
#pragma unroll
        for (int j = 0; j < 8; ++j) ST[c0 + j][row] = tv[j];
    }
    __syncthreads();

    // phase B: split-transpose -> Thn/Tln ([64][N] layout for global_load_lds)
    if (Thn) {
        const int f = t >> 2;           // 0..63
        const int r0 = (t & 3) * 8;     // 0,8,16,24
        ushort_t hh[8], ll[8];
#pragma unroll
        for (int i = 0; i < 8; ++i) f32_split(ST[f][r0 + i], hh[i], ll[i]);
        unsigned wh[4], wl[4];
#pragma unroll
        for (int j = 0; j < 4; ++j) {
            wh[j] = (unsigned)hh[2 * j] | ((unsigned)hh[2 * j + 1] << 16);
            wl[j] = (unsigned)ll[2 * j] | ((unsigned)ll[2 * j + 1] << 16);
        }
        const size_t ob = (size_t)f * NN + rb + r0;
        *(uint4*)(Thn + ob) = make_uint4(wh[0], wh[1], wh[2], wh[3]);
        *(uint4*)(Tln + ob) = make_uint4(wl[0], wl[1], wl[2], wl[3]);
    }

    // phase C: out += t @ Wk
    {
        float4 a0 = *(const float4*)(out + o);
        float4 a1 = *(const float4*)(out + o + 4);
#pragma unroll
        for (int f = 0; f < FF; ++f) {
            const float sv = ST[f][row];
            const float4 w0 = *(const float4*)&WK[f][c0];
            const float4 w1 = *(const float4*)&WK[f][c0 + 4];
            a0.x += sv * w0.x; a0.y += sv * w0.y;
            a0.z += sv * w0.z; a0.w += sv * w0.w;
            a1.x += sv * w1.x; a1.y += sv * w1.y;
            a1.z += sv * w1.z; a1.w += sv * w1.w;
        }
        *(float4*)(out + o) = a0;
        *(float4*)(out + o + 4) = a1;
    }
}

extern "C" void kernel_launch(void* const* d_in, const int* in_sizes, int n_in,
                              void* d_out, int out_size, void* d_ws, size_t ws_size,
                              hipStream_t stream)
{
    const float* x    = (const float*)d_in[0];
    const float* L    = (const float*)d_in[1];
    const float* W    = (const float*)d_in[2];   // (4, 64, 64)
    const float* bias = (const float*)d_in[3];
    float* out = (float*)d_out;

    const size_t M1 = (size_t)NN * FF;           // 1,048,576 elems
    float* wsf = (float*)d_ws;
    float* T1 = wsf;                             // 4 MB
    float* P  = wsf + M1;                        // 4 partials, 16 MB
    ushort_t* ThA = (ushort_t*)(wsf + 5 * M1);   // 2 MB each
    ushort_t* TlA = ThA + M1;
    ushort_t* ThB = TlA + M1;
    ushort_t* TlB = ThB + M1;

    const dim3 gc(NN / 64), bc(256);             // convT_init: 256 blocks
    const dim3 gg(SK * 256), bg(256);            // gemm: 1024 blocks
    const dim3 gp(NN / 32), bp(256);             // post_hop: 512 blocks

    // hop 0: ThA/TlA = splitT(x) ; out = bias + x@W0
    convT_init<<<gc, bc, 0, stream>>>(x, ThA, TlA, W + 0 * FF * FF, bias, out);
    // hop 1: T1 = L@x ; ThB/TlB = splitT(T1) ; out += T1@W1
    cheb_gemm_mfma<<<gg, bg, 0, stream>>>(L, ThA, TlA, P);
    post_hop<<<gp, bp, 0, stream>>>(P, x, W + 1 * FF * FF,
                                    T1, ThB, TlB, out, 1.f, 0.f);
    // hop 2: T2 = 2*(L@T1) - x ; ThA/TlA = splitT(T2) ; out += T2@W2
    cheb_gemm_mfma<<<gg, bg, 0, stream>>>(L, ThB, TlB, P);
    post_hop<<<gp, bp, 0, stream>>>(P, x, W + 2 * FF * FF,
                                    nullptr, ThA, TlA, out, 2.f, -1.f);
    // hop 3: T3 = 2*(L@T2) - T1 ; out += T3@W3
    cheb_gemm_mfma<<<gg, bg, 0, stream>>>(L, ThA, TlA, P);
    post_hop<<<gp, bp, 0, stream>>>(P, T1, W + 3 * FF * FF,
                                    nullptr, nullptr, nullptr, out, 2.f, -1.f);
}